// Round 1
// baseline (837.641 us; speedup 1.0000x reference)
//
#include <hip/hip_runtime.h>

static constexpr int D = 128;

__global__ __launch_bounds__(256) void k_hist(const int* __restrict__ dst, int* __restrict__ hist, int E) {
  int e = blockIdx.x * 256 + threadIdx.x;
  if (e < E) atomicAdd(&hist[dst[e]], 1);
}

// single-block exclusive scan over n counts -> offsets[0..n]
__global__ __launch_bounds__(1024) void k_scan(const int* __restrict__ hist, int* __restrict__ offsets, int n) {
  __shared__ int wsum[16];
  int tid = threadIdx.x, lane = tid & 63, w = tid >> 6;
  int carry = 0;
  for (int base = 0; base < n; base += 1024) {
    int i = base + tid;
    int v = (i < n) ? hist[i] : 0;
    int x = v;
    #pragma unroll
    for (int off = 1; off < 64; off <<= 1) {
      int t = __shfl_up(x, off);
      if (lane >= off) x += t;
    }
    if (lane == 63) wsum[w] = x;
    __syncthreads();
    int wpre = 0, total = 0;
    #pragma unroll
    for (int k = 0; k < 16; ++k) { int s = wsum[k]; total += s; if (k < w) wpre += s; }
    if (i < n) offsets[i] = carry + wpre + x - v;
    carry += total;
    __syncthreads();
  }
  if (tid == 0) offsets[n] = carry;
}

__global__ __launch_bounds__(256) void k_fill(const int* __restrict__ src, const int* __restrict__ dst,
                                              const int* __restrict__ offsets, int* __restrict__ cursor,
                                              int* __restrict__ ssrc, int E) {
  int e = blockIdx.x * 256 + threadIdx.x;
  if (e < E) {
    int d = dst[e];
    int pos = offsets[d] + atomicAdd(&cursor[d], 1);
    ssrc[pos] = src[e];
  }
}

// one wave per node; lane covers dims (2*lane, 2*lane+1)
__global__ __launch_bounds__(256) void k_aggregate(const float* __restrict__ X, const int* __restrict__ offsets,
                                                   const int* __restrict__ ssrc, float* __restrict__ Agg, int n) {
  int wid = (blockIdx.x * 256 + threadIdx.x) >> 6;
  int lane = threadIdx.x & 63;
  if (wid >= n) return;
  int o0 = offsets[wid], o1 = offsets[wid + 1];
  int deg = o1 - o0;
  float ax = 0.f, ay = 0.f;
  for (int eb = 0; eb < deg; eb += 64) {
    int myid = (eb + lane < deg) ? ssrc[o0 + eb + lane] : 0;
    int cnt = min(64, deg - eb);
    for (int j = 0; j < cnt; ++j) {
      int s = __shfl(myid, j);
      float2 v = *(const float2*)&X[(size_t)s * D + lane * 2];
      ax += v.x; ay += v.y;
    }
  }
  float inv = 1.f / (float)max(deg, 1);
  float2 r; r.x = ax * inv; r.y = ay * inv;
  *(float2*)&Agg[(size_t)wid * D + lane * 2] = r;
}

// h_out[n][j] = relu( sum_k Agg[n][k]*Wl[j][k] + sum_k Xin[n][k]*Wr[j][k] + b[j] )
// block: 256 thr = 4 waves; block tile 32 nodes; wave tile 8 nodes x 128 outputs; lane: j=lane & j=lane+64
__global__ __launch_bounds__(256, 3) void k_sage_gemm(const float* __restrict__ Xin, const float* __restrict__ Agg,
                                                      const float* __restrict__ Wl, const float* __restrict__ Wr,
                                                      const float* __restrict__ bias, float* __restrict__ Out, int n) {
  __shared__ float rows[32][256];   // [node][k] : k<128 agg, k>=128 x
  __shared__ float wt[32][132];     // k-major W chunk, padded
  int base = blockIdx.x * 32;
  int tid = threadIdx.x;
  int wave = tid >> 6, lane = tid & 63;
  for (int idx = tid; idx < 32 * 256; idx += 256) {
    int nn = idx >> 8, k = idx & 255;
    int node = base + nn;
    float v = 0.f;
    if (node < n) v = (k < 128) ? Agg[(size_t)node * D + k] : Xin[(size_t)node * D + (k - 128)];
    rows[nn][k] = v;
  }
  float acc0[8], acc1[8];
  #pragma unroll
  for (int i = 0; i < 8; ++i) { acc0[i] = 0.f; acc1[i] = 0.f; }
  int wn0 = wave * 8;
  for (int chunk = 0; chunk < 8; ++chunk) {
    const float* __restrict__ W = (chunk < 4) ? Wl : Wr;
    int kbase = (chunk & 3) * 32;
    int rbase = (chunk < 4) ? 0 : 128;
    __syncthreads();
    for (int idx = tid; idx < 128 * 32; idx += 256) {
      int j = idx >> 5, kk = idx & 31;
      wt[kk][j] = W[j * 128 + kbase + kk];
    }
    __syncthreads();
    #pragma unroll
    for (int kk = 0; kk < 32; kk += 4) {
      float4 r[8];
      #pragma unroll
      for (int nn = 0; nn < 8; ++nn)
        r[nn] = *(const float4*)&rows[wn0 + nn][rbase + kbase + kk];
      float w0[4], w1[4];
      #pragma unroll
      for (int q = 0; q < 4; ++q) { w0[q] = wt[kk + q][lane]; w1[q] = wt[kk + q][lane + 64]; }
      #pragma unroll
      for (int q = 0; q < 4; ++q) {
        #pragma unroll
        for (int nn = 0; nn < 8; ++nn) {
          const float* rp = (const float*)&r[nn];
          acc0[nn] = fmaf(rp[q], w0[q], acc0[nn]);
          acc1[nn] = fmaf(rp[q], w1[q], acc1[nn]);
        }
      }
    }
  }
  float b0 = bias[lane], b1 = bias[lane + 64];
  #pragma unroll
  for (int nn = 0; nn < 8; ++nn) {
    int node = base + wn0 + nn;
    if (node < n) {
      float v0 = fmaxf(acc0[nn] + b0, 0.f);
      float v1 = fmaxf(acc1[nn] + b1, 0.f);
      Out[(size_t)node * D + lane] = v0;
      Out[(size_t)node * D + lane + 64] = v1;
    }
  }
}

__global__ __launch_bounds__(256) void k_gcnt(const int* __restrict__ batch, int* __restrict__ gcnt, int n) {
  int i = blockIdx.x * 256 + threadIdx.x;
  if (i < n) atomicAdd(&gcnt[batch[i]], 1);
}

__global__ __launch_bounds__(256) void k_pool(const float* __restrict__ H, const int* __restrict__ batch,
                                              float* __restrict__ pooled, int n) {
  int idx = blockIdx.x * 256 + threadIdx.x;
  if (idx >= n * 64) return;
  int node = idx >> 6, dp = idx & 63;
  int g = batch[node];
  float2 v = *(const float2*)&H[(size_t)node * D + dp * 2];
  atomicAdd(&pooled[g * D + dp * 2], v.x);
  atomicAdd(&pooled[g * D + dp * 2 + 1], v.y);
}

__global__ __launch_bounds__(64) void k_final(const float* __restrict__ pooled, const int* __restrict__ gcnt,
                                              const float* __restrict__ Wfc, const float* __restrict__ bfc,
                                              float* __restrict__ out, int OUT) {
  int g = blockIdx.x, lane = threadIdx.x;
  float inv = 1.f / (float)max(gcnt[g], 1);
  float2 p = *(const float2*)&pooled[g * D + lane * 2];
  p.x *= inv; p.y *= inv;
  for (int o = 0; o < OUT; ++o) {
    float2 w = *(const float2*)&Wfc[o * D + lane * 2];
    float part = p.x * w.x + p.y * w.y;
    #pragma unroll
    for (int off = 32; off > 0; off >>= 1) part += __shfl_down(part, off);
    if (lane == 0) out[g * OUT + o] = part + bfc[o];
  }
}

extern "C" void kernel_launch(void* const* d_in, const int* in_sizes, int n_in,
                              void* d_out, int out_size, void* d_ws, size_t ws_size,
                              hipStream_t stream) {
  const float* x   = (const float*)d_in[0];
  const int* ei    = (const int*)d_in[1];
  const int* batch = (const int*)d_in[2];
  const float* W1l = (const float*)d_in[3];
  const float* W1r = (const float*)d_in[4];
  const float* b1  = (const float*)d_in[5];
  const float* W2l = (const float*)d_in[6];
  const float* W2r = (const float*)d_in[7];
  const float* b2  = (const float*)d_in[8];
  const float* W3l = (const float*)d_in[9];
  const float* W3r = (const float*)d_in[10];
  const float* b3  = (const float*)d_in[11];
  const float* Wfc = (const float*)d_in[12];
  const float* bfc = (const float*)d_in[13];
  float* out = (float*)d_out;

  int N = in_sizes[0] / D;
  int E = in_sizes[1] / 2;
  int OUT = in_sizes[12] / D;
  int G = out_size / OUT;
  const int* src = ei;
  const int* dst = ei + E;

  float* agg = (float*)d_ws;
  float* h1  = agg + (size_t)N * D;
  float* h2  = h1 + (size_t)N * D;
  int* ssrc  = (int*)(h2 + (size_t)N * D);
  int* hist  = ssrc + E;
  int* offsets = hist + N;
  int* cursor = offsets + (N + 2);
  int* gcnt  = cursor + N;
  float* pooled = (float*)(gcnt + ((G + 1) & ~1));

  hipMemsetAsync(hist, 0, (size_t)N * 4, stream);
  hipMemsetAsync(cursor, 0, (size_t)N * 4, stream);
  hipMemsetAsync(gcnt, 0, (size_t)G * 4, stream);
  hipMemsetAsync(pooled, 0, (size_t)G * D * 4, stream);

  int eb = (E + 255) / 256;
  k_hist<<<eb, 256, 0, stream>>>(dst, hist, E);
  k_scan<<<1, 1024, 0, stream>>>(hist, offsets, N);
  k_fill<<<eb, 256, 0, stream>>>(src, dst, offsets, cursor, ssrc, E);
  k_gcnt<<<(N + 255) / 256, 256, 0, stream>>>(batch, gcnt, N);

  int ab = (N * 64 + 255) / 256;
  int gb = (N + 31) / 32;

  k_aggregate<<<ab, 256, 0, stream>>>(x, offsets, ssrc, agg, N);
  k_sage_gemm<<<gb, 256, 0, stream>>>(x, agg, W1l, W1r, b1, h1, N);

  k_aggregate<<<ab, 256, 0, stream>>>(h1, offsets, ssrc, agg, N);
  k_sage_gemm<<<gb, 256, 0, stream>>>(h1, agg, W2l, W2r, b2, h2, N);

  k_aggregate<<<ab, 256, 0, stream>>>(h2, offsets, ssrc, agg, N);
  k_sage_gemm<<<gb, 256, 0, stream>>>(h2, agg, W3l, W3r, b3, h1, N);

  k_pool<<<ab, 256, 0, stream>>>(h1, batch, pooled, N);
  k_final<<<G, 64, 0, stream>>>(pooled, gcnt, Wfc, bfc, out, OUT);
}

// Round 2
// 547.549 us; speedup vs baseline: 1.5298x; 1.5298x over previous
//
#include <hip/hip_runtime.h>

static constexpr int D = 128;

__global__ __launch_bounds__(256) void k_hist(const int* __restrict__ dst, int* __restrict__ hist, int E) {
  int e = blockIdx.x * 256 + threadIdx.x;
  if (e < E) atomicAdd(&hist[dst[e]], 1);
}

// single-block exclusive scan over n counts -> offsets[0..n]
__global__ __launch_bounds__(1024) void k_scan(const int* __restrict__ hist, int* __restrict__ offsets, int n) {
  __shared__ int wsum[16];
  int tid = threadIdx.x, lane = tid & 63, w = tid >> 6;
  int carry = 0;
  for (int base = 0; base < n; base += 1024) {
    int i = base + tid;
    int v = (i < n) ? hist[i] : 0;
    int x = v;
    #pragma unroll
    for (int off = 1; off < 64; off <<= 1) {
      int t = __shfl_up(x, off);
      if (lane >= off) x += t;
    }
    if (lane == 63) wsum[w] = x;
    __syncthreads();
    int wpre = 0, total = 0;
    #pragma unroll
    for (int k = 0; k < 16; ++k) { int s = wsum[k]; total += s; if (k < w) wpre += s; }
    if (i < n) offsets[i] = carry + wpre + x - v;
    carry += total;
    __syncthreads();
  }
  if (tid == 0) offsets[n] = carry;
}

__global__ __launch_bounds__(256) void k_fill(const int* __restrict__ src, const int* __restrict__ dst,
                                              const int* __restrict__ offsets, int* __restrict__ cursor,
                                              int* __restrict__ ssrc, int E) {
  int e = blockIdx.x * 256 + threadIdx.x;
  if (e < E) {
    int d = dst[e];
    int pos = offsets[d] + atomicAdd(&cursor[d], 1);
    ssrc[pos] = src[e];
  }
}

// one wave per node; lane covers dims (2*lane, 2*lane+1)
__global__ __launch_bounds__(256) void k_aggregate(const float* __restrict__ X, const int* __restrict__ offsets,
                                                   const int* __restrict__ ssrc, float* __restrict__ Agg, int n) {
  int wid = (blockIdx.x * 256 + threadIdx.x) >> 6;
  int lane = threadIdx.x & 63;
  if (wid >= n) return;
  int o0 = offsets[wid], o1 = offsets[wid + 1];
  int deg = o1 - o0;
  float ax = 0.f, ay = 0.f;
  for (int eb = 0; eb < deg; eb += 64) {
    int myid = (eb + lane < deg) ? ssrc[o0 + eb + lane] : 0;
    int cnt = min(64, deg - eb);
    for (int j = 0; j < cnt; ++j) {
      int s = __shfl(myid, j);
      float2 v = *(const float2*)&X[(size_t)s * D + lane * 2];
      ax += v.x; ay += v.y;
    }
  }
  float inv = 1.f / (float)max(deg, 1);
  float2 r; r.x = ax * inv; r.y = ay * inv;
  *(float2*)&Agg[(size_t)wid * D + lane * 2] = r;
}

// h_out[n][j] = relu( sum_k Agg[n][k]*Wl[j][k] + sum_k Xin[n][k]*Wr[j][k] + b[j] )
__global__ __launch_bounds__(256, 3) void k_sage_gemm(const float* __restrict__ Xin, const float* __restrict__ Agg,
                                                      const float* __restrict__ Wl, const float* __restrict__ Wr,
                                                      const float* __restrict__ bias, float* __restrict__ Out, int n) {
  __shared__ float rows[32][256];   // [node][k] : k<128 agg, k>=128 x
  __shared__ float wt[32][132];     // k-major W chunk, padded
  int base = blockIdx.x * 32;
  int tid = threadIdx.x;
  int wave = tid >> 6, lane = tid & 63;
  for (int idx = tid; idx < 32 * 256; idx += 256) {
    int nn = idx >> 8, k = idx & 255;
    int node = base + nn;
    float v = 0.f;
    if (node < n) v = (k < 128) ? Agg[(size_t)node * D + k] : Xin[(size_t)node * D + (k - 128)];
    rows[nn][k] = v;
  }
  float acc0[8], acc1[8];
  #pragma unroll
  for (int i = 0; i < 8; ++i) { acc0[i] = 0.f; acc1[i] = 0.f; }
  int wn0 = wave * 8;
  for (int chunk = 0; chunk < 8; ++chunk) {
    const float* __restrict__ W = (chunk < 4) ? Wl : Wr;
    int kbase = (chunk & 3) * 32;
    int rbase = (chunk < 4) ? 0 : 128;
    __syncthreads();
    for (int idx = tid; idx < 128 * 32; idx += 256) {
      int j = idx >> 5, kk = idx & 31;
      wt[kk][j] = W[j * 128 + kbase + kk];
    }
    __syncthreads();
    #pragma unroll
    for (int kk = 0; kk < 32; kk += 4) {
      float4 r[8];
      #pragma unroll
      for (int nn = 0; nn < 8; ++nn)
        r[nn] = *(const float4*)&rows[wn0 + nn][rbase + kbase + kk];
      float w0[4], w1[4];
      #pragma unroll
      for (int q = 0; q < 4; ++q) { w0[q] = wt[kk + q][lane]; w1[q] = wt[kk + q][lane + 64]; }
      #pragma unroll
      for (int q = 0; q < 4; ++q) {
        #pragma unroll
        for (int nn = 0; nn < 8; ++nn) {
          const float* rp = (const float*)&r[nn];
          acc0[nn] = fmaf(rp[q], w0[q], acc0[nn]);
          acc1[nn] = fmaf(rp[q], w1[q], acc1[nn]);
        }
      }
    }
  }
  float b0 = bias[lane], b1 = bias[lane + 64];
  #pragma unroll
  for (int nn = 0; nn < 8; ++nn) {
    int node = base + wn0 + nn;
    if (node < n) {
      float v0 = fmaxf(acc0[nn] + b0, 0.f);
      float v1 = fmaxf(acc1[nn] + b1, 0.f);
      Out[(size_t)node * D + lane] = v0;
      Out[(size_t)node * D + lane + 64] = v1;
    }
  }
}

// fused mean-pool + FC: one block per graph; batch is sorted so each group is a
// contiguous node range found by binary search. Zero atomics.
__global__ __launch_bounds__(256) void k_pool_fc(const float* __restrict__ H, const int* __restrict__ batch,
                                                 const float* __restrict__ Wfc, const float* __restrict__ bfc,
                                                 float* __restrict__ out, int n, int OUT) {
  __shared__ float wsums[4][128];
  int g = blockIdx.x;
  int tid = threadIdx.x, wave = tid >> 6, lane = tid & 63;
  int a = 0, b = n;
  while (a < b) { int m = (a + b) >> 1; if (batch[m] < g) a = m + 1; else b = m; }
  int lo = a;
  b = n;
  while (a < b) { int m = (a + b) >> 1; if (batch[m] < g + 1) a = m + 1; else b = m; }
  int hi = a;
  float ax = 0.f, ay = 0.f;
  for (int node = lo + wave; node < hi; node += 4) {
    float2 v = *(const float2*)&H[(size_t)node * D + lane * 2];
    ax += v.x; ay += v.y;
  }
  wsums[wave][lane * 2] = ax;
  wsums[wave][lane * 2 + 1] = ay;
  __syncthreads();
  if (wave == 0) {
    float inv = 1.f / (float)max(hi - lo, 1);
    float mx = (wsums[0][lane * 2] + wsums[1][lane * 2] + wsums[2][lane * 2] + wsums[3][lane * 2]) * inv;
    float my = (wsums[0][lane * 2 + 1] + wsums[1][lane * 2 + 1] + wsums[2][lane * 2 + 1] + wsums[3][lane * 2 + 1]) * inv;
    for (int o = 0; o < OUT; ++o) {
      float2 w = *(const float2*)&Wfc[o * D + lane * 2];
      float part = mx * w.x + my * w.y;
      #pragma unroll
      for (int off = 32; off > 0; off >>= 1) part += __shfl_down(part, off);
      if (lane == 0) out[g * OUT + o] = part + bfc[o];
    }
  }
}

extern "C" void kernel_launch(void* const* d_in, const int* in_sizes, int n_in,
                              void* d_out, int out_size, void* d_ws, size_t ws_size,
                              hipStream_t stream) {
  const float* x   = (const float*)d_in[0];
  const int* ei    = (const int*)d_in[1];
  const int* batch = (const int*)d_in[2];
  const float* W1l = (const float*)d_in[3];
  const float* W1r = (const float*)d_in[4];
  const float* b1  = (const float*)d_in[5];
  const float* W2l = (const float*)d_in[6];
  const float* W2r = (const float*)d_in[7];
  const float* b2  = (const float*)d_in[8];
  const float* W3l = (const float*)d_in[9];
  const float* W3r = (const float*)d_in[10];
  const float* b3  = (const float*)d_in[11];
  const float* Wfc = (const float*)d_in[12];
  const float* bfc = (const float*)d_in[13];
  float* out = (float*)d_out;

  int N = in_sizes[0] / D;
  int E = in_sizes[1] / 2;
  int OUT = in_sizes[12] / D;
  int G = out_size / OUT;
  const int* src = ei;
  const int* dst = ei + E;

  float* agg = (float*)d_ws;
  float* h1  = agg + (size_t)N * D;
  float* h2  = h1 + (size_t)N * D;
  int* ssrc  = (int*)(h2 + (size_t)N * D);
  int* hist  = ssrc + E;
  int* offsets = hist + N;
  int* cursor = offsets + (N + 2);

  hipMemsetAsync(hist, 0, (size_t)N * 4, stream);
  hipMemsetAsync(cursor, 0, (size_t)N * 4, stream);

  int eb = (E + 255) / 256;
  k_hist<<<eb, 256, 0, stream>>>(dst, hist, E);
  k_scan<<<1, 1024, 0, stream>>>(hist, offsets, N);
  k_fill<<<eb, 256, 0, stream>>>(src, dst, offsets, cursor, ssrc, E);

  int ab = (N * 64 + 255) / 256;
  int gb = (N + 31) / 32;

  k_aggregate<<<ab, 256, 0, stream>>>(x, offsets, ssrc, agg, N);
  k_sage_gemm<<<gb, 256, 0, stream>>>(x, agg, W1l, W1r, b1, h1, N);

  k_aggregate<<<ab, 256, 0, stream>>>(h1, offsets, ssrc, agg, N);
  k_sage_gemm<<<gb, 256, 0, stream>>>(h1, agg, W2l, W2r, b2, h2, N);

  k_aggregate<<<ab, 256, 0, stream>>>(h2, offsets, ssrc, agg, N);
  k_sage_gemm<<<gb, 256, 0, stream>>>(h2, agg, W3l, W3r, b3, h1, N);

  k_pool_fc<<<G, 256, 0, stream>>>(h1, batch, Wfc, bfc, out, N, OUT);
}

// Round 3
// 365.132 us; speedup vs baseline: 2.2941x; 1.4996x over previous
//
#include <hip/hip_runtime.h>

static constexpr int D = 128;

typedef __attribute__((ext_vector_type(8))) short short8;
typedef __attribute__((ext_vector_type(4))) float f32x4;

__device__ inline ushort f2bf(float f) {
  union { float f; unsigned u; } v; v.f = f;
  unsigned r = v.u + 0x7FFF + ((v.u >> 16) & 1);
  return (ushort)(r >> 16);
}
__device__ inline float bf2f_lo(unsigned p) {
  union { unsigned u; float f; } v; v.u = p << 16; return v.f;
}
__device__ inline float bf2f_hi(unsigned p) {
  union { unsigned u; float f; } v; v.u = p & 0xFFFF0000u; return v.f;
}

__global__ __launch_bounds__(256) void k_hist(const int* __restrict__ dst, int* __restrict__ hist, int E) {
  int e = blockIdx.x * 256 + threadIdx.x;
  if (e < E) atomicAdd(&hist[dst[e]], 1);
}

__global__ __launch_bounds__(1024) void k_scan(const int* __restrict__ hist, int* __restrict__ offsets, int n) {
  __shared__ int wsum[16];
  int tid = threadIdx.x, lane = tid & 63, w = tid >> 6;
  int carry = 0;
  for (int base = 0; base < n; base += 1024) {
    int i = base + tid;
    int v = (i < n) ? hist[i] : 0;
    int x = v;
    #pragma unroll
    for (int off = 1; off < 64; off <<= 1) {
      int t = __shfl_up(x, off);
      if (lane >= off) x += t;
    }
    if (lane == 63) wsum[w] = x;
    __syncthreads();
    int wpre = 0, total = 0;
    #pragma unroll
    for (int k = 0; k < 16; ++k) { int s = wsum[k]; total += s; if (k < w) wpre += s; }
    if (i < n) offsets[i] = carry + wpre + x - v;
    carry += total;
    __syncthreads();
  }
  if (tid == 0) offsets[n] = carry;
}

__global__ __launch_bounds__(256) void k_fill(const int* __restrict__ src, const int* __restrict__ dst,
                                              const int* __restrict__ offsets, int* __restrict__ cursor,
                                              int* __restrict__ ssrc, int E) {
  int e = blockIdx.x * 256 + threadIdx.x;
  if (e < E) {
    int d = dst[e];
    int pos = offsets[d] + atomicAdd(&cursor[d], 1);
    ssrc[pos] = src[e];
  }
}

// f32 -> bf16 bulk convert (n4 = n/4 float4 groups)
__global__ __launch_bounds__(256) void k_cvt(const float* __restrict__ in, ushort* __restrict__ out, int n4) {
  int i = blockIdx.x * 256 + threadIdx.x;
  if (i >= n4) return;
  float4 v = *(const float4*)&in[i * 4];
  ushort4 o;
  o.x = f2bf(v.x); o.y = f2bf(v.y); o.z = f2bf(v.z); o.w = f2bf(v.w);
  *(ushort4*)&out[i * 4] = o;
}

struct WPtrs { const float* s[6]; ushort* d[6]; };
__global__ __launch_bounds__(256) void k_cvt_w(WPtrs p) {
  int idx = blockIdx.x * 256 + threadIdx.x;  // float4 index over 6 x 16384 floats
  int mat = idx >> 12;                        // 4096 float4 per matrix
  int off = (idx & 4095) * 4;
  float4 v = *(const float4*)&p.s[mat][off];
  ushort4 o;
  o.x = f2bf(v.x); o.y = f2bf(v.y); o.z = f2bf(v.z); o.w = f2bf(v.w);
  *(ushort4*)&p.d[mat][off] = o;
}

// one wave per node; lane covers dims (2*lane, 2*lane+1); bf16 in/out, f32 accum
__global__ __launch_bounds__(256) void k_aggregate_bf(const ushort* __restrict__ X, const int* __restrict__ offsets,
                                                      const int* __restrict__ ssrc, ushort* __restrict__ Agg, int n) {
  int wid = (blockIdx.x * 256 + threadIdx.x) >> 6;
  int lane = threadIdx.x & 63;
  if (wid >= n) return;
  int o0 = offsets[wid], o1 = offsets[wid + 1];
  int deg = o1 - o0;
  float ax = 0.f, ay = 0.f;
  for (int eb = 0; eb < deg; eb += 64) {
    int myid = (eb + lane < deg) ? ssrc[o0 + eb + lane] : 0;
    int cnt = min(64, deg - eb);
    for (int j = 0; j < cnt; ++j) {
      int s = __shfl(myid, j);
      unsigned v = *(const unsigned*)&X[(size_t)s * D + lane * 2];
      ax += bf2f_lo(v);
      ay += bf2f_hi(v);
    }
  }
  float inv = 1.f / (float)max(deg, 1);
  unsigned o = (unsigned)f2bf(ax * inv) | ((unsigned)f2bf(ay * inv) << 16);
  *(unsigned*)&Agg[(size_t)wid * D + lane * 2] = o;
}

// Out = relu(Agg @ Wl^T + Xin @ Wr^T + b), bf16 in, f32 accum, bf16 out.
// 625 blocks x 64 nodes; 4 waves in 2Mx2N grid: wave = 32 nodes x 64 outputs.
// Fragments loaded directly from global (row-major A and W give contiguous 16B/lane).
__global__ __launch_bounds__(256) void k_gemm_mfma(const ushort* __restrict__ Abf, const ushort* __restrict__ Xbf,
                                                   const ushort* __restrict__ Wl, const ushort* __restrict__ Wr,
                                                   const float* __restrict__ bias, ushort* __restrict__ Out, int n) {
  int tid = threadIdx.x;
  int wave = tid >> 6, lane = tid & 63;
  int wm = wave >> 1, wn = wave & 1;
  int m_base = blockIdx.x * 64 + wm * 32;
  int n_base = wn * 64;
  int r = lane & 15, kg = lane >> 4;

  f32x4 acc[2][4];
  #pragma unroll
  for (int i = 0; i < 2; ++i)
    #pragma unroll
    for (int j = 0; j < 4; ++j) acc[i][j] = (f32x4){0.f, 0.f, 0.f, 0.f};

  const ushort* As[2] = {Abf, Xbf};
  const ushort* Ws[2] = {Wl, Wr};
  #pragma unroll
  for (int half = 0; half < 2; ++half) {
    const ushort* A = As[half];
    const ushort* W = Ws[half];
    #pragma unroll
    for (int k0 = 0; k0 < 128; k0 += 32) {
      int kk = k0 + kg * 8;
      short8 a[2], b[4];
      #pragma unroll
      for (int fm = 0; fm < 2; ++fm)
        a[fm] = *(const short8*)&A[(size_t)(m_base + fm * 16 + r) * D + kk];
      #pragma unroll
      for (int fn = 0; fn < 4; ++fn)
        b[fn] = *(const short8*)&W[(size_t)(n_base + fn * 16 + r) * D + kk];
      #pragma unroll
      for (int fm = 0; fm < 2; ++fm)
        #pragma unroll
        for (int fn = 0; fn < 4; ++fn)
          acc[fm][fn] = __builtin_amdgcn_mfma_f32_16x16x32_bf16(a[fm], b[fn], acc[fm][fn], 0, 0, 0);
    }
  }
  // C/D layout: col = lane&15 (output j), row = (lane>>4)*4 + reg (node)
  #pragma unroll
  for (int fn = 0; fn < 4; ++fn) {
    int j = n_base + fn * 16 + r;
    float bj = bias[j];
    #pragma unroll
    for (int fm = 0; fm < 2; ++fm) {
      #pragma unroll
      for (int q = 0; q < 4; ++q) {
        int node = m_base + fm * 16 + kg * 4 + q;
        float v = fmaxf(acc[fm][fn][q] + bj, 0.f);
        Out[(size_t)node * D + j] = f2bf(v);
      }
    }
  }
}

// fused mean-pool + FC, one block per graph (batch sorted -> contiguous range)
__global__ __launch_bounds__(256) void k_pool_fc(const ushort* __restrict__ H, const int* __restrict__ batch,
                                                 const float* __restrict__ Wfc, const float* __restrict__ bfc,
                                                 float* __restrict__ out, int n, int OUT) {
  __shared__ float wsums[4][128];
  int g = blockIdx.x;
  int tid = threadIdx.x, wave = tid >> 6, lane = tid & 63;
  int a = 0, b = n;
  while (a < b) { int m = (a + b) >> 1; if (batch[m] < g) a = m + 1; else b = m; }
  int lo = a;
  b = n;
  while (a < b) { int m = (a + b) >> 1; if (batch[m] < g + 1) a = m + 1; else b = m; }
  int hi = a;
  float ax = 0.f, ay = 0.f;
  for (int node = lo + wave; node < hi; node += 4) {
    unsigned v = *(const unsigned*)&H[(size_t)node * D + lane * 2];
    ax += bf2f_lo(v);
    ay += bf2f_hi(v);
  }
  wsums[wave][lane * 2] = ax;
  wsums[wave][lane * 2 + 1] = ay;
  __syncthreads();
  if (wave == 0) {
    float inv = 1.f / (float)max(hi - lo, 1);
    float mx = (wsums[0][lane * 2] + wsums[1][lane * 2] + wsums[2][lane * 2] + wsums[3][lane * 2]) * inv;
    float my = (wsums[0][lane * 2 + 1] + wsums[1][lane * 2 + 1] + wsums[2][lane * 2 + 1] + wsums[3][lane * 2 + 1]) * inv;
    for (int o = 0; o < OUT; ++o) {
      float2 w = *(const float2*)&Wfc[o * D + lane * 2];
      float part = mx * w.x + my * w.y;
      #pragma unroll
      for (int off = 32; off > 0; off >>= 1) part += __shfl_down(part, off);
      if (lane == 0) out[g * OUT + o] = part + bfc[o];
    }
  }
}

extern "C" void kernel_launch(void* const* d_in, const int* in_sizes, int n_in,
                              void* d_out, int out_size, void* d_ws, size_t ws_size,
                              hipStream_t stream) {
  const float* x   = (const float*)d_in[0];
  const int* ei    = (const int*)d_in[1];
  const int* batch = (const int*)d_in[2];
  const float* W1l = (const float*)d_in[3];
  const float* W1r = (const float*)d_in[4];
  const float* b1  = (const float*)d_in[5];
  const float* W2l = (const float*)d_in[6];
  const float* W2r = (const float*)d_in[7];
  const float* b2  = (const float*)d_in[8];
  const float* W3l = (const float*)d_in[9];
  const float* W3r = (const float*)d_in[10];
  const float* b3  = (const float*)d_in[11];
  const float* Wfc = (const float*)d_in[12];
  const float* bfc = (const float*)d_in[13];
  float* out = (float*)d_out;

  int N = in_sizes[0] / D;
  int E = in_sizes[1] / 2;
  int OUT = in_sizes[12] / D;
  int G = out_size / OUT;
  const int* src = ei;
  const int* dst = ei + E;

  // workspace layout (bf16 = ushort)
  ushort* xb  = (ushort*)d_ws;
  ushort* agg = xb + (size_t)N * D;
  ushort* h1  = agg + (size_t)N * D;
  ushort* h2  = h1 + (size_t)N * D;
  ushort* wb  = h2 + (size_t)N * D;          // 6 * 128*128 bf16 weights
  int* ssrc   = (int*)(wb + 6 * 128 * 128);
  int* hist   = ssrc + E;
  int* offsets = hist + N;
  int* cursor = offsets + (N + 2);

  ushort* wl1 = wb + 0 * 16384; ushort* wr1 = wb + 1 * 16384;
  ushort* wl2 = wb + 2 * 16384; ushort* wr2 = wb + 3 * 16384;
  ushort* wl3 = wb + 4 * 16384; ushort* wr3 = wb + 5 * 16384;

  hipMemsetAsync(hist, 0, (size_t)N * 4, stream);
  hipMemsetAsync(cursor, 0, (size_t)N * 4, stream);

  int eb = (E + 255) / 256;
  k_hist<<<eb, 256, 0, stream>>>(dst, hist, E);
  k_scan<<<1, 1024, 0, stream>>>(hist, offsets, N);
  k_fill<<<eb, 256, 0, stream>>>(src, dst, offsets, cursor, ssrc, E);

  int n4 = N * D / 4;
  k_cvt<<<(n4 + 255) / 256, 256, 0, stream>>>(x, xb, n4);
  WPtrs wp;
  wp.s[0] = W1l; wp.s[1] = W1r; wp.s[2] = W2l; wp.s[3] = W2r; wp.s[4] = W3l; wp.s[5] = W3r;
  wp.d[0] = wl1; wp.d[1] = wr1; wp.d[2] = wl2; wp.d[3] = wr2; wp.d[4] = wl3; wp.d[5] = wr3;
  k_cvt_w<<<96, 256, 0, stream>>>(wp);

  int ab = (N * 64 + 255) / 256;
  int gb = N / 64;

  k_aggregate_bf<<<ab, 256, 0, stream>>>(xb, offsets, ssrc, agg, N);
  k_gemm_mfma<<<gb, 256, 0, stream>>>(agg, xb, wl1, wr1, b1, h1, N);

  k_aggregate_bf<<<ab, 256, 0, stream>>>(h1, offsets, ssrc, agg, N);
  k_gemm_mfma<<<gb, 256, 0, stream>>>(agg, h1, wl2, wr2, b2, h2, N);

  k_aggregate_bf<<<ab, 256, 0, stream>>>(h2, offsets, ssrc, agg, N);
  k_gemm_mfma<<<gb, 256, 0, stream>>>(agg, h2, wl3, wr3, b3, h1, N);

  k_pool_fc<<<G, 256, 0, stream>>>(h1, batch, Wfc, bfc, out, N, OUT);
}

// Round 4
// 331.316 us; speedup vs baseline: 2.5282x; 1.1021x over previous
//
#include <hip/hip_runtime.h>

static constexpr int D = 128;
static constexpr int PS = 32;   // pool slices per graph

typedef __attribute__((ext_vector_type(8))) short short8;
typedef __attribute__((ext_vector_type(4))) float f32x4;

__device__ inline ushort f2bf(float f) {
  union { float f; unsigned u; } v; v.f = f;
  unsigned r = v.u + 0x7FFF + ((v.u >> 16) & 1);
  return (ushort)(r >> 16);
}
__device__ inline float bf2f_lo(unsigned p) {
  union { unsigned u; float f; } v; v.u = p << 16; return v.f;
}
__device__ inline float bf2f_hi(unsigned p) {
  union { unsigned u; float f; } v; v.u = p & 0xFFFF0000u; return v.f;
}

__global__ __launch_bounds__(256) void k_hist(const int* __restrict__ dst, int* __restrict__ hist, int E) {
  int e = blockIdx.x * 256 + threadIdx.x;
  if (e < E) atomicAdd(&hist[dst[e]], 1);
}

__global__ __launch_bounds__(1024) void k_scan(const int* __restrict__ hist, int* __restrict__ offsets, int n) {
  __shared__ int wsum[16];
  int tid = threadIdx.x, lane = tid & 63, w = tid >> 6;
  int carry = 0;
  for (int base = 0; base < n; base += 1024) {
    int i = base + tid;
    int v = (i < n) ? hist[i] : 0;
    int x = v;
    #pragma unroll
    for (int off = 1; off < 64; off <<= 1) {
      int t = __shfl_up(x, off);
      if (lane >= off) x += t;
    }
    if (lane == 63) wsum[w] = x;
    __syncthreads();
    int wpre = 0, total = 0;
    #pragma unroll
    for (int k = 0; k < 16; ++k) { int s = wsum[k]; total += s; if (k < w) wpre += s; }
    if (i < n) offsets[i] = carry + wpre + x - v;
    carry += total;
    __syncthreads();
  }
  if (tid == 0) offsets[n] = carry;
}

__global__ __launch_bounds__(256) void k_fill(const int* __restrict__ src, const int* __restrict__ dst,
                                              const int* __restrict__ offsets, int* __restrict__ cursor,
                                              int* __restrict__ ssrc, int E) {
  int e = blockIdx.x * 256 + threadIdx.x;
  if (e < E) {
    int d = dst[e];
    int pos = offsets[d] + atomicAdd(&cursor[d], 1);
    ssrc[pos] = src[e];
  }
}

__global__ __launch_bounds__(256) void k_cvt(const float* __restrict__ in, ushort* __restrict__ out, int n4) {
  int i = blockIdx.x * 256 + threadIdx.x;
  if (i >= n4) return;
  float4 v = *(const float4*)&in[i * 4];
  ushort4 o;
  o.x = f2bf(v.x); o.y = f2bf(v.y); o.z = f2bf(v.z); o.w = f2bf(v.w);
  *(ushort4*)&out[i * 4] = o;
}

struct WPtrs { const float* s[6]; ushort* d[6]; };
__global__ __launch_bounds__(256) void k_cvt_w(WPtrs p) {
  int idx = blockIdx.x * 256 + threadIdx.x;
  int mat = idx >> 12;
  int off = (idx & 4095) * 4;
  float4 v = *(const float4*)&p.s[mat][off];
  ushort4 o;
  o.x = f2bf(v.x); o.y = f2bf(v.y); o.z = f2bf(v.z); o.w = f2bf(v.w);
  *(ushort4*)&p.d[mat][off] = o;
}

// one wave per node; lane covers dims (2*lane, 2*lane+1); bf16 in/out, f32 accum
__global__ __launch_bounds__(256) void k_aggregate_bf(const ushort* __restrict__ X, const int* __restrict__ offsets,
                                                      const int* __restrict__ ssrc, ushort* __restrict__ Agg, int n) {
  int wid = (blockIdx.x * 256 + threadIdx.x) >> 6;
  int lane = threadIdx.x & 63;
  if (wid >= n) return;
  int o0 = offsets[wid], o1 = offsets[wid + 1];
  int deg = o1 - o0;
  float ax = 0.f, ay = 0.f;
  for (int eb = 0; eb < deg; eb += 64) {
    int myid = (eb + lane < deg) ? ssrc[o0 + eb + lane] : 0;
    int cnt = min(64, deg - eb);
    for (int j = 0; j < cnt; ++j) {
      int s = __shfl(myid, j);
      unsigned v = *(const unsigned*)&X[(size_t)s * D + lane * 2];
      ax += bf2f_lo(v);
      ay += bf2f_hi(v);
    }
  }
  float inv = 1.f / (float)max(deg, 1);
  unsigned o = (unsigned)f2bf(ax * inv) | ((unsigned)f2bf(ay * inv) << 16);
  *(unsigned*)&Agg[(size_t)wid * D + lane * 2] = o;
}

// Out = relu(Agg @ Wl^T + Xin @ Wr^T + b), bf16 in, f32 accum, bf16 out.
__global__ __launch_bounds__(256) void k_gemm_mfma(const ushort* __restrict__ Abf, const ushort* __restrict__ Xbf,
                                                   const ushort* __restrict__ Wl, const ushort* __restrict__ Wr,
                                                   const float* __restrict__ bias, ushort* __restrict__ Out, int n) {
  int tid = threadIdx.x;
  int wave = tid >> 6, lane = tid & 63;
  int wm = wave >> 1, wn = wave & 1;
  int m_base = blockIdx.x * 64 + wm * 32;
  int n_base = wn * 64;
  int r = lane & 15, kg = lane >> 4;

  f32x4 acc[2][4];
  #pragma unroll
  for (int i = 0; i < 2; ++i)
    #pragma unroll
    for (int j = 0; j < 4; ++j) acc[i][j] = (f32x4){0.f, 0.f, 0.f, 0.f};

  const ushort* As[2] = {Abf, Xbf};
  const ushort* Ws[2] = {Wl, Wr};
  #pragma unroll
  for (int half = 0; half < 2; ++half) {
    const ushort* A = As[half];
    const ushort* W = Ws[half];
    #pragma unroll
    for (int k0 = 0; k0 < 128; k0 += 32) {
      int kk = k0 + kg * 8;
      short8 a[2], b[4];
      #pragma unroll
      for (int fm = 0; fm < 2; ++fm)
        a[fm] = *(const short8*)&A[(size_t)(m_base + fm * 16 + r) * D + kk];
      #pragma unroll
      for (int fn = 0; fn < 4; ++fn)
        b[fn] = *(const short8*)&W[(size_t)(n_base + fn * 16 + r) * D + kk];
      #pragma unroll
      for (int fm = 0; fm < 2; ++fm)
        #pragma unroll
        for (int fn = 0; fn < 4; ++fn)
          acc[fm][fn] = __builtin_amdgcn_mfma_f32_16x16x32_bf16(a[fm], b[fn], acc[fm][fn], 0, 0, 0);
    }
  }
  #pragma unroll
  for (int fn = 0; fn < 4; ++fn) {
    int j = n_base + fn * 16 + r;
    float bj = bias[j];
    #pragma unroll
    for (int fm = 0; fm < 2; ++fm) {
      #pragma unroll
      for (int q = 0; q < 4; ++q) {
        int node = m_base + fm * 16 + kg * 4 + q;
        float v = fmaxf(acc[fm][fn][q] + bj, 0.f);
        Out[(size_t)node * D + j] = f2bf(v);
      }
    }
  }
}

// pool stage 1: block (g, s) sums slice s of graph g's node range -> partial[g*PS+s][128] f32
__global__ __launch_bounds__(256) void k_pool_partial(const ushort* __restrict__ H, const int* __restrict__ batch,
                                                      float* __restrict__ partial, int n) {
  __shared__ float wsums[4][128];
  int g = blockIdx.x / PS, s = blockIdx.x % PS;
  int tid = threadIdx.x, wave = tid >> 6, lane = tid & 63;
  int a = 0, b = n;
  while (a < b) { int m = (a + b) >> 1; if (batch[m] < g) a = m + 1; else b = m; }
  int lo = a;
  b = n;
  while (a < b) { int m = (a + b) >> 1; if (batch[m] < g + 1) a = m + 1; else b = m; }
  int hi = a;
  int len = hi - lo;
  int chunk = (len + PS - 1) / PS;
  int a0 = lo + s * chunk;
  int a1 = min(a0 + chunk, hi);
  float ax = 0.f, ay = 0.f;
  for (int node = a0 + wave; node < a1; node += 4) {
    unsigned v = *(const unsigned*)&H[(size_t)node * D + lane * 2];
    ax += bf2f_lo(v);
    ay += bf2f_hi(v);
  }
  wsums[wave][lane * 2] = ax;
  wsums[wave][lane * 2 + 1] = ay;
  __syncthreads();
  if (tid < 128) {
    float v = wsums[0][tid] + wsums[1][tid] + wsums[2][tid] + wsums[3][tid];
    partial[(size_t)blockIdx.x * 128 + tid] = v;
  }
}

// pool stage 2: block per graph; reduce PS partials, mean, FC (OUT outputs)
__global__ __launch_bounds__(256) void k_pool_fc2(const float* __restrict__ partial, const int* __restrict__ batch,
                                                  const float* __restrict__ Wfc, const float* __restrict__ bfc,
                                                  float* __restrict__ out, int n, int OUT) {
  __shared__ float pooled[128];
  int g = blockIdx.x;
  int tid = threadIdx.x, lane = tid & 63;
  int a = 0, b = n;
  while (a < b) { int m = (a + b) >> 1; if (batch[m] < g) a = m + 1; else b = m; }
  int lo = a;
  b = n;
  while (a < b) { int m = (a + b) >> 1; if (batch[m] < g + 1) a = m + 1; else b = m; }
  int hi = a;
  float inv = 1.f / (float)max(hi - lo, 1);
  if (tid < 128) {
    float v = 0.f;
    #pragma unroll
    for (int s = 0; s < PS; ++s) v += partial[(size_t)(g * PS + s) * 128 + tid];
    pooled[tid] = v * inv;
  }
  __syncthreads();
  if (tid < 64) {
    float2 p = *(const float2*)&pooled[lane * 2];
    for (int o = 0; o < OUT; ++o) {
      float2 w = *(const float2*)&Wfc[o * D + lane * 2];
      float part = p.x * w.x + p.y * w.y;
      #pragma unroll
      for (int off = 32; off > 0; off >>= 1) part += __shfl_down(part, off);
      if (lane == 0) out[g * OUT + o] = part + bfc[o];
    }
  }
}

extern "C" void kernel_launch(void* const* d_in, const int* in_sizes, int n_in,
                              void* d_out, int out_size, void* d_ws, size_t ws_size,
                              hipStream_t stream) {
  const float* x   = (const float*)d_in[0];
  const int* ei    = (const int*)d_in[1];
  const int* batch = (const int*)d_in[2];
  const float* W1l = (const float*)d_in[3];
  const float* W1r = (const float*)d_in[4];
  const float* b1  = (const float*)d_in[5];
  const float* W2l = (const float*)d_in[6];
  const float* W2r = (const float*)d_in[7];
  const float* b2  = (const float*)d_in[8];
  const float* W3l = (const float*)d_in[9];
  const float* W3r = (const float*)d_in[10];
  const float* b3  = (const float*)d_in[11];
  const float* Wfc = (const float*)d_in[12];
  const float* bfc = (const float*)d_in[13];
  float* out = (float*)d_out;

  int N = in_sizes[0] / D;
  int E = in_sizes[1] / 2;
  int OUT = in_sizes[12] / D;
  int G = out_size / OUT;
  const int* src = ei;
  const int* dst = ei + E;

  ushort* xb  = (ushort*)d_ws;
  ushort* agg = xb + (size_t)N * D;
  ushort* h1  = agg + (size_t)N * D;
  ushort* h2  = h1 + (size_t)N * D;
  ushort* wb  = h2 + (size_t)N * D;
  int* ssrc   = (int*)(wb + 6 * 128 * 128);
  int* hist   = ssrc + E;
  int* offsets = hist + N;
  int* cursor = offsets + (N + 2);
  float* partial = (float*)(cursor + N + 2);   // G*PS*128 f32

  ushort* wl1 = wb + 0 * 16384; ushort* wr1 = wb + 1 * 16384;
  ushort* wl2 = wb + 2 * 16384; ushort* wr2 = wb + 3 * 16384;
  ushort* wl3 = wb + 4 * 16384; ushort* wr3 = wb + 5 * 16384;

  hipMemsetAsync(hist, 0, (size_t)N * 4, stream);
  hipMemsetAsync(cursor, 0, (size_t)N * 4, stream);

  int eb = (E + 255) / 256;
  k_hist<<<eb, 256, 0, stream>>>(dst, hist, E);
  k_scan<<<1, 1024, 0, stream>>>(hist, offsets, N);
  k_fill<<<eb, 256, 0, stream>>>(src, dst, offsets, cursor, ssrc, E);

  int n4 = N * D / 4;
  k_cvt<<<(n4 + 255) / 256, 256, 0, stream>>>(x, xb, n4);
  WPtrs wp;
  wp.s[0] = W1l; wp.s[1] = W1r; wp.s[2] = W2l; wp.s[3] = W2r; wp.s[4] = W3l; wp.s[5] = W3r;
  wp.d[0] = wl1; wp.d[1] = wr1; wp.d[2] = wl2; wp.d[3] = wr2; wp.d[4] = wl3; wp.d[5] = wr3;
  k_cvt_w<<<96, 256, 0, stream>>>(wp);

  int ab = (N * 64 + 255) / 256;
  int gb = N / 64;

  k_aggregate_bf<<<ab, 256, 0, stream>>>(xb, offsets, ssrc, agg, N);
  k_gemm_mfma<<<gb, 256, 0, stream>>>(agg, xb, wl1, wr1, b1, h1, N);

  k_aggregate_bf<<<ab, 256, 0, stream>>>(h1, offsets, ssrc, agg, N);
  k_gemm_mfma<<<gb, 256, 0, stream>>>(agg, h1, wl2, wr2, b2, h2, N);

  k_aggregate_bf<<<ab, 256, 0, stream>>>(h2, offsets, ssrc, agg, N);
  k_gemm_mfma<<<gb, 256, 0, stream>>>(agg, h2, wl3, wr3, b3, h1, N);

  k_pool_partial<<<G * PS, 256, 0, stream>>>(h1, batch, partial, N);
  k_pool_fc2<<<G, 256, 0, stream>>>(partial, batch, Wfc, bfc, out, N, OUT);
}

// Round 5
// 284.134 us; speedup vs baseline: 2.9480x; 1.1661x over previous
//
#include <hip/hip_runtime.h>

static constexpr int D = 128;
static constexpr int PS = 32;   // pool slices per graph

typedef __attribute__((ext_vector_type(8))) short short8;
typedef __attribute__((ext_vector_type(4))) float f32x4;

__device__ inline ushort f2bf(float f) {
  union { float f; unsigned u; } v; v.f = f;
  unsigned r = v.u + 0x7FFF + ((v.u >> 16) & 1);
  return (ushort)(r >> 16);
}
__device__ inline float bf2f_lo(unsigned p) {
  union { unsigned u; float f; } v; v.u = p << 16; return v.f;
}
__device__ inline float bf2f_hi(unsigned p) {
  union { unsigned u; float f; } v; v.u = p & 0xFFFF0000u; return v.f;
}

__global__ __launch_bounds__(256) void k_hist(const int* __restrict__ dst, int* __restrict__ hist, int E) {
  int e = blockIdx.x * 256 + threadIdx.x;
  if (e < E) atomicAdd(&hist[dst[e]], 1);
}

__global__ __launch_bounds__(1024) void k_scan(const int* __restrict__ hist, int* __restrict__ offsets, int n) {
  __shared__ int wsum[16];
  int tid = threadIdx.x, lane = tid & 63, w = tid >> 6;
  int carry = 0;
  for (int base = 0; base < n; base += 1024) {
    int i = base + tid;
    int v = (i < n) ? hist[i] : 0;
    int x = v;
    #pragma unroll
    for (int off = 1; off < 64; off <<= 1) {
      int t = __shfl_up(x, off);
      if (lane >= off) x += t;
    }
    if (lane == 63) wsum[w] = x;
    __syncthreads();
    int wpre = 0, total = 0;
    #pragma unroll
    for (int k = 0; k < 16; ++k) { int s = wsum[k]; total += s; if (k < w) wpre += s; }
    if (i < n) offsets[i] = carry + wpre + x - v;
    carry += total;
    __syncthreads();
  }
  if (tid == 0) offsets[n] = carry;
}

__global__ __launch_bounds__(256) void k_fill(const int* __restrict__ src, const int* __restrict__ dst,
                                              const int* __restrict__ offsets, int* __restrict__ cursor,
                                              int* __restrict__ ssrc, int E) {
  int e = blockIdx.x * 256 + threadIdx.x;
  if (e < E) {
    int d = dst[e];
    int pos = offsets[d] + atomicAdd(&cursor[d], 1);
    ssrc[pos] = src[e];
  }
}

__global__ __launch_bounds__(256) void k_cvt(const float* __restrict__ in, ushort* __restrict__ out, int n4) {
  int i = blockIdx.x * 256 + threadIdx.x;
  if (i >= n4) return;
  float4 v = *(const float4*)&in[i * 4];
  ushort4 o;
  o.x = f2bf(v.x); o.y = f2bf(v.y); o.z = f2bf(v.z); o.w = f2bf(v.w);
  *(ushort4*)&out[i * 4] = o;
}

struct WPtrs { const float* s[6]; ushort* d[6]; };
__global__ __launch_bounds__(256) void k_cvt_w(WPtrs p) {
  int idx = blockIdx.x * 256 + threadIdx.x;
  int mat = idx >> 12;
  int off = (idx & 4095) * 4;
  float4 v = *(const float4*)&p.s[mat][off];
  ushort4 o;
  o.x = f2bf(v.x); o.y = f2bf(v.y); o.z = f2bf(v.z); o.w = f2bf(v.w);
  *(ushort4*)&p.d[mat][off] = o;
}

// one wave per node; 4 x 16-lane groups each gather one full 256B row (16B/lane).
// Prefetched: next batch's loads issue before current batch's accumulate.
__global__ __launch_bounds__(256) void k_aggregate_bf(const ushort* __restrict__ X, const int* __restrict__ offsets,
                                                      const int* __restrict__ ssrc, ushort* __restrict__ Agg, int n) {
  int wid = (blockIdx.x * 256 + threadIdx.x) >> 6;
  int lane = threadIdx.x & 63;
  if (wid >= n) return;
  int q = lane >> 4, r = lane & 15;          // group, lane-in-group
  int o0 = offsets[wid], o1 = offsets[wid + 1];
  int deg = o1 - o0;

  float acc[8];
  #pragma unroll
  for (int i = 0; i < 8; ++i) acc[i] = 0.f;

  uint4 cur = {0u, 0u, 0u, 0u};
  if (q < deg) {
    int sid = ssrc[o0 + q];
    cur = *(const uint4*)&X[(size_t)sid * D + r * 8];
  }
  for (int base = 0; base < deg; base += 4) {
    uint4 nxt = {0u, 0u, 0u, 0u};
    int nb = base + 4 + q;
    if (nb < deg) {
      int sid = ssrc[o0 + nb];
      nxt = *(const uint4*)&X[(size_t)sid * D + r * 8];
    }
    acc[0] += bf2f_lo(cur.x); acc[1] += bf2f_hi(cur.x);
    acc[2] += bf2f_lo(cur.y); acc[3] += bf2f_hi(cur.y);
    acc[4] += bf2f_lo(cur.z); acc[5] += bf2f_hi(cur.z);
    acc[6] += bf2f_lo(cur.w); acc[7] += bf2f_hi(cur.w);
    cur = nxt;
  }
  // sum the 4 groups (lanes differing in bits 4-5)
  #pragma unroll
  for (int i = 0; i < 8; ++i) {
    acc[i] += __shfl_xor(acc[i], 16);
    acc[i] += __shfl_xor(acc[i], 32);
  }
  if (q == 0) {
    float inv = 1.f / (float)max(deg, 1);
    uint4 o;
    o.x = (unsigned)f2bf(acc[0] * inv) | ((unsigned)f2bf(acc[1] * inv) << 16);
    o.y = (unsigned)f2bf(acc[2] * inv) | ((unsigned)f2bf(acc[3] * inv) << 16);
    o.z = (unsigned)f2bf(acc[4] * inv) | ((unsigned)f2bf(acc[5] * inv) << 16);
    o.w = (unsigned)f2bf(acc[6] * inv) | ((unsigned)f2bf(acc[7] * inv) << 16);
    *(uint4*)&Agg[(size_t)wid * D + r * 8] = o;
  }
}

// Out = relu(Agg @ Wl^T + Xin @ Wr^T + b), bf16 in, f32 accum, bf16 out.
__global__ __launch_bounds__(256) void k_gemm_mfma(const ushort* __restrict__ Abf, const ushort* __restrict__ Xbf,
                                                   const ushort* __restrict__ Wl, const ushort* __restrict__ Wr,
                                                   const float* __restrict__ bias, ushort* __restrict__ Out, int n) {
  int tid = threadIdx.x;
  int wave = tid >> 6, lane = tid & 63;
  int wm = wave >> 1, wn = wave & 1;
  int m_base = blockIdx.x * 64 + wm * 32;
  int n_base = wn * 64;
  int r = lane & 15, kg = lane >> 4;

  f32x4 acc[2][4];
  #pragma unroll
  for (int i = 0; i < 2; ++i)
    #pragma unroll
    for (int j = 0; j < 4; ++j) acc[i][j] = (f32x4){0.f, 0.f, 0.f, 0.f};

  const ushort* As[2] = {Abf, Xbf};
  const ushort* Ws[2] = {Wl, Wr};
  #pragma unroll
  for (int half = 0; half < 2; ++half) {
    const ushort* A = As[half];
    const ushort* W = Ws[half];
    #pragma unroll
    for (int k0 = 0; k0 < 128; k0 += 32) {
      int kk = k0 + kg * 8;
      short8 a[2], b[4];
      #pragma unroll
      for (int fm = 0; fm < 2; ++fm)
        a[fm] = *(const short8*)&A[(size_t)(m_base + fm * 16 + r) * D + kk];
      #pragma unroll
      for (int fn = 0; fn < 4; ++fn)
        b[fn] = *(const short8*)&W[(size_t)(n_base + fn * 16 + r) * D + kk];
      #pragma unroll
      for (int fm = 0; fm < 2; ++fm)
        #pragma unroll
        for (int fn = 0; fn < 4; ++fn)
          acc[fm][fn] = __builtin_amdgcn_mfma_f32_16x16x32_bf16(a[fm], b[fn], acc[fm][fn], 0, 0, 0);
    }
  }
  #pragma unroll
  for (int fn = 0; fn < 4; ++fn) {
    int j = n_base + fn * 16 + r;
    float bj = bias[j];
    #pragma unroll
    for (int fm = 0; fm < 2; ++fm) {
      #pragma unroll
      for (int q = 0; q < 4; ++q) {
        int node = m_base + fm * 16 + kg * 4 + q;
        float v = fmaxf(acc[fm][fn][q] + bj, 0.f);
        Out[(size_t)node * D + j] = f2bf(v);
      }
    }
  }
}

// pool stage 1: block (g, s) sums slice s of graph g's node range -> partial[g*PS+s][128] f32
__global__ __launch_bounds__(256) void k_pool_partial(const ushort* __restrict__ H, const int* __restrict__ batch,
                                                      float* __restrict__ partial, int n) {
  __shared__ float wsums[4][128];
  int g = blockIdx.x / PS, s = blockIdx.x % PS;
  int tid = threadIdx.x, wave = tid >> 6, lane = tid & 63;
  int a = 0, b = n;
  while (a < b) { int m = (a + b) >> 1; if (batch[m] < g) a = m + 1; else b = m; }
  int lo = a;
  b = n;
  while (a < b) { int m = (a + b) >> 1; if (batch[m] < g + 1) a = m + 1; else b = m; }
  int hi = a;
  int len = hi - lo;
  int chunk = (len + PS - 1) / PS;
  int a0 = lo + s * chunk;
  int a1 = min(a0 + chunk, hi);
  float ax = 0.f, ay = 0.f;
  for (int node = a0 + wave; node < a1; node += 4) {
    unsigned v = *(const unsigned*)&H[(size_t)node * D + lane * 2];
    ax += bf2f_lo(v);
    ay += bf2f_hi(v);
  }
  wsums[wave][lane * 2] = ax;
  wsums[wave][lane * 2 + 1] = ay;
  __syncthreads();
  if (tid < 128) {
    float v = wsums[0][tid] + wsums[1][tid] + wsums[2][tid] + wsums[3][tid];
    partial[(size_t)blockIdx.x * 128 + tid] = v;
  }
}

// pool stage 2: block per graph; reduce PS partials, mean, FC (OUT outputs)
__global__ __launch_bounds__(256) void k_pool_fc2(const float* __restrict__ partial, const int* __restrict__ batch,
                                                  const float* __restrict__ Wfc, const float* __restrict__ bfc,
                                                  float* __restrict__ out, int n, int OUT) {
  __shared__ float pooled[128];
  int g = blockIdx.x;
  int tid = threadIdx.x, lane = tid & 63;
  int a = 0, b = n;
  while (a < b) { int m = (a + b) >> 1; if (batch[m] < g) a = m + 1; else b = m; }
  int lo = a;
  b = n;
  while (a < b) { int m = (a + b) >> 1; if (batch[m] < g + 1) a = m + 1; else b = m; }
  int hi = a;
  float inv = 1.f / (float)max(hi - lo, 1);
  if (tid < 128) {
    float v = 0.f;
    #pragma unroll
    for (int s = 0; s < PS; ++s) v += partial[(size_t)(g * PS + s) * 128 + tid];
    pooled[tid] = v * inv;
  }
  __syncthreads();
  if (tid < 64) {
    float2 p = *(const float2*)&pooled[lane * 2];
    for (int o = 0; o < OUT; ++o) {
      float2 w = *(const float2*)&Wfc[o * D + lane * 2];
      float part = p.x * w.x + p.y * w.y;
      #pragma unroll
      for (int off = 32; off > 0; off >>= 1) part += __shfl_down(part, off);
      if (lane == 0) out[g * OUT + o] = part + bfc[o];
    }
  }
}

extern "C" void kernel_launch(void* const* d_in, const int* in_sizes, int n_in,
                              void* d_out, int out_size, void* d_ws, size_t ws_size,
                              hipStream_t stream) {
  const float* x   = (const float*)d_in[0];
  const int* ei    = (const int*)d_in[1];
  const int* batch = (const int*)d_in[2];
  const float* W1l = (const float*)d_in[3];
  const float* W1r = (const float*)d_in[4];
  const float* b1  = (const float*)d_in[5];
  const float* W2l = (const float*)d_in[6];
  const float* W2r = (const float*)d_in[7];
  const float* b2  = (const float*)d_in[8];
  const float* W3l = (const float*)d_in[9];
  const float* W3r = (const float*)d_in[10];
  const float* b3  = (const float*)d_in[11];
  const float* Wfc = (const float*)d_in[12];
  const float* bfc = (const float*)d_in[13];
  float* out = (float*)d_out;

  int N = in_sizes[0] / D;
  int E = in_sizes[1] / 2;
  int OUT = in_sizes[12] / D;
  int G = out_size / OUT;
  const int* src = ei;
  const int* dst = ei + E;

  ushort* xb  = (ushort*)d_ws;
  ushort* agg = xb + (size_t)N * D;
  ushort* h1  = agg + (size_t)N * D;
  ushort* h2  = h1 + (size_t)N * D;
  ushort* wb  = h2 + (size_t)N * D;
  int* ssrc   = (int*)(wb + 6 * 128 * 128);
  int* hist   = ssrc + E;
  int* offsets = hist + N;
  int* cursor = offsets + (N + 2);
  float* partial = (float*)(cursor + N + 2);   // G*PS*128 f32

  ushort* wl1 = wb + 0 * 16384; ushort* wr1 = wb + 1 * 16384;
  ushort* wl2 = wb + 2 * 16384; ushort* wr2 = wb + 3 * 16384;
  ushort* wl3 = wb + 4 * 16384; ushort* wr3 = wb + 5 * 16384;

  hipMemsetAsync(hist, 0, (size_t)N * 4, stream);
  hipMemsetAsync(cursor, 0, (size_t)N * 4, stream);

  int eb = (E + 255) / 256;
  k_hist<<<eb, 256, 0, stream>>>(dst, hist, E);
  k_scan<<<1, 1024, 0, stream>>>(hist, offsets, N);
  k_fill<<<eb, 256, 0, stream>>>(src, dst, offsets, cursor, ssrc, E);

  int n4 = N * D / 4;
  k_cvt<<<(n4 + 255) / 256, 256, 0, stream>>>(x, xb, n4);
  WPtrs wp;
  wp.s[0] = W1l; wp.s[1] = W1r; wp.s[2] = W2l; wp.s[3] = W2r; wp.s[4] = W3l; wp.s[5] = W3r;
  wp.d[0] = wl1; wp.d[1] = wr1; wp.d[2] = wl2; wp.d[3] = wr2; wp.d[4] = wl3; wp.d[5] = wr3;
  k_cvt_w<<<96, 256, 0, stream>>>(wp);

  int ab = (N * 64 + 255) / 256;
  int gb = N / 64;

  k_aggregate_bf<<<ab, 256, 0, stream>>>(xb, offsets, ssrc, agg, N);
  k_gemm_mfma<<<gb, 256, 0, stream>>>(agg, xb, wl1, wr1, b1, h1, N);

  k_aggregate_bf<<<ab, 256, 0, stream>>>(h1, offsets, ssrc, agg, N);
  k_gemm_mfma<<<gb, 256, 0, stream>>>(agg, h1, wl2, wr2, b2, h2, N);

  k_aggregate_bf<<<ab, 256, 0, stream>>>(h2, offsets, ssrc, agg, N);
  k_gemm_mfma<<<gb, 256, 0, stream>>>(agg, h2, wl3, wr3, b3, h1, N);

  k_pool_partial<<<G * PS, 256, 0, stream>>>(h1, batch, partial, N);
  k_pool_fc2<<<G, 256, 0, stream>>>(partial, batch, Wfc, bfc, out, N, OUT);
}

// Round 6
// 263.079 us; speedup vs baseline: 3.1840x; 1.0800x over previous
//
#include <hip/hip_runtime.h>

static constexpr int D = 128;
static constexpr int PS = 32;   // pool slices per graph

typedef __attribute__((ext_vector_type(8))) short short8;
typedef __attribute__((ext_vector_type(4))) float f32x4;

__device__ inline ushort f2bf(float f) {
  union { float f; unsigned u; } v; v.f = f;
  unsigned r = v.u + 0x7FFF + ((v.u >> 16) & 1);
  return (ushort)(r >> 16);
}
__device__ inline float bf2f_lo(unsigned p) {
  union { unsigned u; float f; } v; v.u = p << 16; return v.f;
}
__device__ inline float bf2f_hi(unsigned p) {
  union { unsigned u; float f; } v; v.u = p & 0xFFFF0000u; return v.f;
}

struct WPtrs { const float* s[6]; ushort* d[6]; };

// fused prep: [0,nxb) cvt x -> bf16 ; [nxb,nxb+96) cvt weights ; rest: dst histogram
__global__ __launch_bounds__(256) void k_prep(const float* __restrict__ x, ushort* __restrict__ xb, WPtrs p,
                                              const int* __restrict__ dst, int* __restrict__ hist,
                                              int n4x, int E) {
  int b = blockIdx.x, tid = threadIdx.x;
  int nxb = (n4x + 255) / 256;
  if (b < nxb) {
    int i = b * 256 + tid;
    if (i < n4x) {
      float4 v = *(const float4*)&x[i * 4];
      ushort4 o;
      o.x = f2bf(v.x); o.y = f2bf(v.y); o.z = f2bf(v.z); o.w = f2bf(v.w);
      *(ushort4*)&xb[i * 4] = o;
    }
  } else if (b < nxb + 96) {
    int idx = (b - nxb) * 256 + tid;
    int mat = idx >> 12;
    int off = (idx & 4095) * 4;
    float4 v = *(const float4*)&p.s[mat][off];
    ushort4 o;
    o.x = f2bf(v.x); o.y = f2bf(v.y); o.z = f2bf(v.z); o.w = f2bf(v.w);
    *(ushort4*)&p.d[mat][off] = o;
  } else {
    int e = (b - nxb - 96) * 256 + tid;
    if (e < E) atomicAdd(&hist[dst[e]], 1);
  }
}

// exclusive scan, 8 elements per thread, single block
__global__ __launch_bounds__(1024) void k_scan(const int* __restrict__ hist, int* __restrict__ offsets, int n) {
  __shared__ int wsum[16];
  int tid = threadIdx.x, lane = tid & 63, w = tid >> 6;
  int carry = 0;
  for (int base = 0; base < n; base += 8192) {
    int i0 = base + tid * 8;
    int v[8];
    #pragma unroll
    for (int j = 0; j < 8; ++j) { int i = i0 + j; v[j] = (i < n) ? hist[i] : 0; }
    int s = 0;
    #pragma unroll
    for (int j = 0; j < 8; ++j) { int t = v[j]; v[j] = s; s += t; }   // v[j]=excl within thread
    int x = s;
    #pragma unroll
    for (int off = 1; off < 64; off <<= 1) {
      int t = __shfl_up(x, off);
      if (lane >= off) x += t;
    }
    if (lane == 63) wsum[w] = x;
    __syncthreads();
    int wpre = 0, total = 0;
    #pragma unroll
    for (int k = 0; k < 16; ++k) { int t = wsum[k]; total += t; if (k < w) wpre += t; }
    int pre = carry + wpre + x - s;
    #pragma unroll
    for (int j = 0; j < 8; ++j) { int i = i0 + j; if (i < n) offsets[i] = pre + v[j]; }
    carry += total;
    __syncthreads();
  }
  if (tid == 0) offsets[n] = carry;
}

__global__ __launch_bounds__(256) void k_fill(const int* __restrict__ src, const int* __restrict__ dst,
                                              const int* __restrict__ offsets, int* __restrict__ cursor,
                                              int* __restrict__ ssrc, int E) {
  int e = blockIdx.x * 256 + threadIdx.x;
  if (e < E) {
    int d = dst[e];
    int pos = offsets[d] + atomicAdd(&cursor[d], 1);
    ssrc[pos] = src[e];
  }
}

// one wave per node; 4 x 16-lane groups, 16 edges (4 x 1KB gathers) in flight per iter;
// edge ids for up to 64 edges preloaded in one register, distributed via shfl.
__global__ __launch_bounds__(256) void k_aggregate_bf(const ushort* __restrict__ X, const int* __restrict__ offsets,
                                                      const int* __restrict__ ssrc, ushort* __restrict__ Agg, int n) {
  int wid = (blockIdx.x * 256 + threadIdx.x) >> 6;
  int lane = threadIdx.x & 63;
  if (wid >= n) return;
  int q = lane >> 4, r = lane & 15;
  int o0 = offsets[wid], deg = offsets[wid + 1] - o0;

  float acc[8];
  #pragma unroll
  for (int i = 0; i < 8; ++i) acc[i] = 0.f;

  for (int c0 = 0; c0 < deg; c0 += 64) {
    int cn = min(64, deg - c0);
    int myid = (lane < cn) ? ssrc[o0 + c0 + lane] : 0;
    for (int j = 0; j < cn; j += 16) {
      uint4 buf[4];
      #pragma unroll
      for (int t = 0; t < 4; ++t) {
        int e = j + t * 4 + q;
        buf[t] = (uint4){0u, 0u, 0u, 0u};
        if (e < cn) {
          int s = __shfl(myid, e);
          buf[t] = *(const uint4*)&X[(size_t)s * D + r * 8];
        }
      }
      #pragma unroll
      for (int t = 0; t < 4; ++t) {
        acc[0] += bf2f_lo(buf[t].x); acc[1] += bf2f_hi(buf[t].x);
        acc[2] += bf2f_lo(buf[t].y); acc[3] += bf2f_hi(buf[t].y);
        acc[4] += bf2f_lo(buf[t].z); acc[5] += bf2f_hi(buf[t].z);
        acc[6] += bf2f_lo(buf[t].w); acc[7] += bf2f_hi(buf[t].w);
      }
    }
  }
  #pragma unroll
  for (int i = 0; i < 8; ++i) {
    acc[i] += __shfl_xor(acc[i], 16);
    acc[i] += __shfl_xor(acc[i], 32);
  }
  if (q == 0) {
    float inv = 1.f / (float)max(deg, 1);
    uint4 o;
    o.x = (unsigned)f2bf(acc[0] * inv) | ((unsigned)f2bf(acc[1] * inv) << 16);
    o.y = (unsigned)f2bf(acc[2] * inv) | ((unsigned)f2bf(acc[3] * inv) << 16);
    o.z = (unsigned)f2bf(acc[4] * inv) | ((unsigned)f2bf(acc[5] * inv) << 16);
    o.w = (unsigned)f2bf(acc[6] * inv) | ((unsigned)f2bf(acc[7] * inv) << 16);
    *(uint4*)&Agg[(size_t)wid * D + r * 8] = o;
  }
}

// Out = relu(Agg @ Wl^T + Xin @ Wr^T + b), bf16 in, f32 accum, bf16 out.
__global__ __launch_bounds__(256) void k_gemm_mfma(const ushort* __restrict__ Abf, const ushort* __restrict__ Xbf,
                                                   const ushort* __restrict__ Wl, const ushort* __restrict__ Wr,
                                                   const float* __restrict__ bias, ushort* __restrict__ Out, int n) {
  int tid = threadIdx.x;
  int wave = tid >> 6, lane = tid & 63;
  int wm = wave >> 1, wn = wave & 1;
  int m_base = blockIdx.x * 64 + wm * 32;
  int n_base = wn * 64;
  int r = lane & 15, kg = lane >> 4;

  f32x4 acc[2][4];
  #pragma unroll
  for (int i = 0; i < 2; ++i)
    #pragma unroll
    for (int j = 0; j < 4; ++j) acc[i][j] = (f32x4){0.f, 0.f, 0.f, 0.f};

  const ushort* As[2] = {Abf, Xbf};
  const ushort* Ws[2] = {Wl, Wr};
  #pragma unroll
  for (int half = 0; half < 2; ++half) {
    const ushort* A = As[half];
    const ushort* W = Ws[half];
    #pragma unroll
    for (int k0 = 0; k0 < 128; k0 += 32) {
      int kk = k0 + kg * 8;
      short8 a[2], b[4];
      #pragma unroll
      for (int fm = 0; fm < 2; ++fm)
        a[fm] = *(const short8*)&A[(size_t)(m_base + fm * 16 + r) * D + kk];
      #pragma unroll
      for (int fn = 0; fn < 4; ++fn)
        b[fn] = *(const short8*)&W[(size_t)(n_base + fn * 16 + r) * D + kk];
      #pragma unroll
      for (int fm = 0; fm < 2; ++fm)
        #pragma unroll
        for (int fn = 0; fn < 4; ++fn)
          acc[fm][fn] = __builtin_amdgcn_mfma_f32_16x16x32_bf16(a[fm], b[fn], acc[fm][fn], 0, 0, 0);
    }
  }
  #pragma unroll
  for (int fn = 0; fn < 4; ++fn) {
    int j = n_base + fn * 16 + r;
    float bj = bias[j];
    #pragma unroll
    for (int fm = 0; fm < 2; ++fm) {
      #pragma unroll
      for (int q = 0; q < 4; ++q) {
        int node = m_base + fm * 16 + kg * 4 + q;
        float v = fmaxf(acc[fm][fn][q] + bj, 0.f);
        Out[(size_t)node * D + j] = f2bf(v);
      }
    }
  }
}

__global__ __launch_bounds__(256) void k_pool_partial(const ushort* __restrict__ H, const int* __restrict__ batch,
                                                      float* __restrict__ partial, int n) {
  __shared__ float wsums[4][128];
  int g = blockIdx.x / PS, s = blockIdx.x % PS;
  int tid = threadIdx.x, wave = tid >> 6, lane = tid & 63;
  int a = 0, b = n;
  while (a < b) { int m = (a + b) >> 1; if (batch[m] < g) a = m + 1; else b = m; }
  int lo = a;
  b = n;
  while (a < b) { int m = (a + b) >> 1; if (batch[m] < g + 1) a = m + 1; else b = m; }
  int hi = a;
  int len = hi - lo;
  int chunk = (len + PS - 1) / PS;
  int a0 = lo + s * chunk;
  int a1 = min(a0 + chunk, hi);
  float ax = 0.f, ay = 0.f;
  for (int node = a0 + wave; node < a1; node += 4) {
    unsigned v = *(const unsigned*)&H[(size_t)node * D + lane * 2];
    ax += bf2f_lo(v);
    ay += bf2f_hi(v);
  }
  wsums[wave][lane * 2] = ax;
  wsums[wave][lane * 2 + 1] = ay;
  __syncthreads();
  if (tid < 128) {
    float v = wsums[0][tid] + wsums[1][tid] + wsums[2][tid] + wsums[3][tid];
    partial[(size_t)blockIdx.x * 128 + tid] = v;
  }
}

__global__ __launch_bounds__(256) void k_pool_fc2(const float* __restrict__ partial, const int* __restrict__ batch,
                                                  const float* __restrict__ Wfc, const float* __restrict__ bfc,
                                                  float* __restrict__ out, int n, int OUT) {
  __shared__ float pooled[128];
  int g = blockIdx.x;
  int tid = threadIdx.x, lane = tid & 63;
  int a = 0, b = n;
  while (a < b) { int m = (a + b) >> 1; if (batch[m] < g) a = m + 1; else b = m; }
  int lo = a;
  b = n;
  while (a < b) { int m = (a + b) >> 1; if (batch[m] < g + 1) a = m + 1; else b = m; }
  int hi = a;
  float inv = 1.f / (float)max(hi - lo, 1);
  if (tid < 128) {
    float v = 0.f;
    #pragma unroll
    for (int s = 0; s < PS; ++s) v += partial[(size_t)(g * PS + s) * 128 + tid];
    pooled[tid] = v * inv;
  }
  __syncthreads();
  if (tid < 64) {
    float2 p = *(const float2*)&pooled[lane * 2];
    for (int o = 0; o < OUT; ++o) {
      float2 w = *(const float2*)&Wfc[o * D + lane * 2];
      float part = p.x * w.x + p.y * w.y;
      #pragma unroll
      for (int off = 32; off > 0; off >>= 1) part += __shfl_down(part, off);
      if (lane == 0) out[g * OUT + o] = part + bfc[o];
    }
  }
}

extern "C" void kernel_launch(void* const* d_in, const int* in_sizes, int n_in,
                              void* d_out, int out_size, void* d_ws, size_t ws_size,
                              hipStream_t stream) {
  const float* x   = (const float*)d_in[0];
  const int* ei    = (const int*)d_in[1];
  const int* batch = (const int*)d_in[2];
  const float* W1l = (const float*)d_in[3];
  const float* W1r = (const float*)d_in[4];
  const float* b1  = (const float*)d_in[5];
  const float* W2l = (const float*)d_in[6];
  const float* W2r = (const float*)d_in[7];
  const float* b2  = (const float*)d_in[8];
  const float* W3l = (const float*)d_in[9];
  const float* W3r = (const float*)d_in[10];
  const float* b3  = (const float*)d_in[11];
  const float* Wfc = (const float*)d_in[12];
  const float* bfc = (const float*)d_in[13];
  float* out = (float*)d_out;

  int N = in_sizes[0] / D;
  int E = in_sizes[1] / 2;
  int OUT = in_sizes[12] / D;
  int G = out_size / OUT;
  const int* src = ei;
  const int* dst = ei + E;

  ushort* xb  = (ushort*)d_ws;
  ushort* agg = xb + (size_t)N * D;
  ushort* h1  = agg + (size_t)N * D;
  ushort* h2  = h1 + (size_t)N * D;
  ushort* wb  = h2 + (size_t)N * D;
  int* ssrc   = (int*)(wb + 6 * 128 * 128);
  int* hist   = ssrc + E;
  int* cursor = hist + N;          // adjacent to hist: one memset covers both
  int* offsets = cursor + N;
  float* partial = (float*)(offsets + N + 2);   // G*PS*128 f32

  ushort* wl1 = wb + 0 * 16384; ushort* wr1 = wb + 1 * 16384;
  ushort* wl2 = wb + 2 * 16384; ushort* wr2 = wb + 3 * 16384;
  ushort* wl3 = wb + 4 * 16384; ushort* wr3 = wb + 5 * 16384;

  hipMemsetAsync(hist, 0, (size_t)2 * N * 4, stream);

  WPtrs wp;
  wp.s[0] = W1l; wp.s[1] = W1r; wp.s[2] = W2l; wp.s[3] = W2r; wp.s[4] = W3l; wp.s[5] = W3r;
  wp.d[0] = wl1; wp.d[1] = wr1; wp.d[2] = wl2; wp.d[3] = wr2; wp.d[4] = wl3; wp.d[5] = wr3;

  int n4 = N * D / 4;
  int nxb = (n4 + 255) / 256;
  int eb = (E + 255) / 256;
  k_prep<<<nxb + 96 + eb, 256, 0, stream>>>(x, xb, wp, dst, hist, n4, E);
  k_scan<<<1, 1024, 0, stream>>>(hist, offsets, N);
  k_fill<<<eb, 256, 0, stream>>>(src, dst, offsets, cursor, ssrc, E);

  int ab = (N * 64 + 255) / 256;
  int gb = N / 64;

  k_aggregate_bf<<<ab, 256, 0, stream>>>(xb, offsets, ssrc, agg, N);
  k_gemm_mfma<<<gb, 256, 0, stream>>>(agg, xb, wl1, wr1, b1, h1, N);

  k_aggregate_bf<<<ab, 256, 0, stream>>>(h1, offsets, ssrc, agg, N);
  k_gemm_mfma<<<gb, 256, 0, stream>>>(agg, h1, wl2, wr2, b2, h2, N);

  k_aggregate_bf<<<ab, 256, 0, stream>>>(h2, offsets, ssrc, agg, N);
  k_gemm_mfma<<<gb, 256, 0, stream>>>(agg, h2, wl3, wr3, b3, h1, N);

  k_pool_partial<<<G * PS, 256, 0, stream>>>(h1, batch, partial, N);
  k_pool_fc2<<<G, 256, 0, stream>>>(partial, batch, Wfc, bfc, out, N, OUT);
}